// Round 1
// baseline (859.905 us; speedup 1.0000x reference)
//
#include <hip/hip_runtime.h>

// ---------------------------------------------------------------------------
// GCN: h = lrelu(x@Win+bin); 2x { y=lrelu(h); h += sum_k S^k(y) @ Wk + bk };
//      out = h@Wout+bout.   S = sum-aggregation over edges (src->dst).
// fp32 everywhere (no fp32 MFMA on CDNA4 -> vector GEMM).
// CSR built per-launch; aggregation is gather-based (no fp32 atomics).
// ---------------------------------------------------------------------------

__device__ __forceinline__ float lrelu(float v) { return v > 0.f ? v : 0.01f * v; }

// ---------------- GEMM: C[N,128] (op)= A[N,128] @ W[128,128] + bias ----------
// MODE 0: C = lrelu(A@W + b)   (readin)
// MODE 1: C += A@W + b         (tap accumulate into h)
// MODE 2: C = A@W + b          (readout)
// Tile: 64 rows x 128 cols, KC=32, 256 threads, each thread 4 rows x 8 cols.
template <int MODE>
__global__ __launch_bounds__(256) void gemm128(const float* __restrict__ A,
                                               const float* __restrict__ W,
                                               const float* __restrict__ bias,
                                               float* __restrict__ C, int N) {
  __shared__ float As[32][68];    // [k][m], padded row stride 68 (16B-aligned)
  __shared__ float Bs[32][128];   // [k][c]
  const int tid = threadIdx.x;
  const int tx = tid & 15;        // col group: cols tx*4..+3 and 64+tx*4..+3
  const int ty = tid >> 4;        // row group: rows ty*4..+3
  const int row0 = blockIdx.x * 64;

  float acc[4][8];
#pragma unroll
  for (int i = 0; i < 4; i++)
#pragma unroll
    for (int j = 0; j < 8; j++) acc[i][j] = 0.f;

  for (int kc = 0; kc < 128; kc += 32) {
    // stage A tile (64 rows x 32 k), transposed into As[k][m]
#pragma unroll
    for (int t = 0; t < 2; t++) {
      int idx = tid + t * 256;            // 0..511 float4 slots
      int m = idx >> 3;                   // tile row 0..63
      int j = idx & 7;                    // float4 within 32-k chunk
      int r = row0 + m;
      if (r >= N) r = N - 1;              // clamp (stores guarded later)
      float4 v = *((const float4*)(A + (size_t)r * 128 + kc) + j);
      As[j * 4 + 0][m] = v.x;
      As[j * 4 + 1][m] = v.y;
      As[j * 4 + 2][m] = v.z;
      As[j * 4 + 3][m] = v.w;
    }
    // stage B tile (32 k x 128 cols), direct copy
#pragma unroll
    for (int t = 0; t < 4; t++) {
      int idx = tid + t * 256;            // 0..1023 float4 slots
      int k = idx >> 5;                   // 0..31
      int c4 = idx & 31;                  // float4 col
      ((float4*)Bs[k])[c4] = ((const float4*)(W + (size_t)(kc + k) * 128))[c4];
    }
    __syncthreads();
#pragma unroll 8
    for (int k = 0; k < 32; k++) {
      float4 a = *(const float4*)&As[k][ty * 4];
      float4 b0 = *(const float4*)&Bs[k][tx * 4];
      float4 b1 = *(const float4*)&Bs[k][64 + tx * 4];
      float av[4] = {a.x, a.y, a.z, a.w};
      float bv[8] = {b0.x, b0.y, b0.z, b0.w, b1.x, b1.y, b1.z, b1.w};
#pragma unroll
      for (int i = 0; i < 4; i++)
#pragma unroll
        for (int j = 0; j < 8; j++) acc[i][j] = fmaf(av[i], bv[j], acc[i][j]);
    }
    __syncthreads();
  }

  const float4* bias4 = (const float4*)bias;
  const float4 bb0 = bias4[tx];
  const float4 bb1 = bias4[16 + tx];
#pragma unroll
  for (int i = 0; i < 4; i++) {
    int r = row0 + ty * 4 + i;
    if (r >= N) continue;
    float4* C4 = (float4*)(C + (size_t)r * 128);
    float4 o0, o1;
    o0.x = acc[i][0] + bb0.x; o0.y = acc[i][1] + bb0.y;
    o0.z = acc[i][2] + bb0.z; o0.w = acc[i][3] + bb0.w;
    o1.x = acc[i][4] + bb1.x; o1.y = acc[i][5] + bb1.y;
    o1.z = acc[i][6] + bb1.z; o1.w = acc[i][7] + bb1.w;
    if (MODE == 0) {
      o0.x = lrelu(o0.x); o0.y = lrelu(o0.y); o0.z = lrelu(o0.z); o0.w = lrelu(o0.w);
      o1.x = lrelu(o1.x); o1.y = lrelu(o1.y); o1.z = lrelu(o1.z); o1.w = lrelu(o1.w);
    } else if (MODE == 1) {
      float4 c0 = C4[tx], c1 = C4[16 + tx];
      o0.x += c0.x; o0.y += c0.y; o0.z += c0.z; o0.w += c0.w;
      o1.x += c1.x; o1.y += c1.y; o1.z += c1.z; o1.w += c1.w;
    }
    C4[tx] = o0;
    C4[16 + tx] = o1;
  }
}

// ---------------- elementwise leaky relu ----------------
__global__ __launch_bounds__(256) void lrelu_k(const float* __restrict__ in,
                                               float* __restrict__ out, int n4) {
  int i = blockIdx.x * 256 + threadIdx.x;
  if (i < n4) {
    float4 v = ((const float4*)in)[i];
    v.x = lrelu(v.x); v.y = lrelu(v.y); v.z = lrelu(v.z); v.w = lrelu(v.w);
    ((float4*)out)[i] = v;
  }
}

// ---------------- CSR build ----------------
__global__ __launch_bounds__(256) void hist_k(const int* __restrict__ dst,
                                              int* __restrict__ deg, int E) {
  int e = blockIdx.x * 256 + threadIdx.x;
  if (e < E) atomicAdd(&deg[dst[e]], 1);
}

__global__ __launch_bounds__(256) void scan1_k(const int* __restrict__ deg,
                                               int* __restrict__ rowp,
                                               int* __restrict__ partials, int N) {
  __shared__ int sm[256];
  int i = blockIdx.x * 256 + threadIdx.x;
  int v = (i < N) ? deg[i] : 0;
  int x = v;
  sm[threadIdx.x] = v;
  __syncthreads();
  for (int off = 1; off < 256; off <<= 1) {
    int t = (threadIdx.x >= off) ? sm[threadIdx.x - off] : 0;
    __syncthreads();
    x += t;
    sm[threadIdx.x] = x;
    __syncthreads();
  }
  if (i < N) rowp[i] = x - v;  // block-local exclusive
  if (threadIdx.x == 255) partials[blockIdx.x] = x;
}

__global__ __launch_bounds__(256) void scan2_k(int* __restrict__ partials, int P) {
  __shared__ int sm[256];
  int i = threadIdx.x;
  int v = (i < P) ? partials[i] : 0;
  int x = v;
  sm[i] = v;
  __syncthreads();
  for (int off = 1; off < 256; off <<= 1) {
    int t = (i >= off) ? sm[i - off] : 0;
    __syncthreads();
    x += t;
    sm[i] = x;
    __syncthreads();
  }
  if (i < P) partials[i] = x - v;  // exclusive
}

__global__ __launch_bounds__(256) void scan3_k(int* __restrict__ rowp,
                                               const int* __restrict__ partials,
                                               int* __restrict__ cursor, int N, int E) {
  int i = blockIdx.x * 256 + threadIdx.x;
  if (i < N) {
    int v = rowp[i] + partials[blockIdx.x];
    rowp[i] = v;
    cursor[i] = v;
  }
  if (i == 0) rowp[N] = E;
}

__global__ __launch_bounds__(256) void scatter_k(const int* __restrict__ src,
                                                 const int* __restrict__ dst,
                                                 int* __restrict__ cursor,
                                                 int* __restrict__ esrc, int E) {
  int e = blockIdx.x * 256 + threadIdx.x;
  if (e < E) {
    int pos = atomicAdd(&cursor[dst[e]], 1);
    esrc[pos] = src[e];
  }
}

// ---------------- aggregation: out[n] = sum_{j in rowp[n]..rowp[n+1]} y[esrc[j]]
// 32 lanes per node (float4 each), 8 nodes per 256-thread block.
__global__ __launch_bounds__(256) void agg_k(const float* __restrict__ y,
                                             float* __restrict__ out,
                                             const int* __restrict__ rowp,
                                             const int* __restrict__ esrc, int N) {
  int t = threadIdx.x;
  int node = blockIdx.x * 8 + (t >> 5);
  if (node >= N) return;
  int lane = t & 31;
  int beg = rowp[node], end = rowp[node + 1];
  float4 s = {0.f, 0.f, 0.f, 0.f};
  for (int j = beg; j < end; j++) {
    int srcn = esrc[j];
    float4 v = ((const float4*)(y + (size_t)srcn * 128))[lane];
    s.x += v.x; s.y += v.y; s.z += v.z; s.w += v.w;
  }
  ((float4*)(out + (size_t)node * 128))[lane] = s;
}

// ---------------------------------------------------------------------------
extern "C" void kernel_launch(void* const* d_in, const int* in_sizes, int n_in,
                              void* d_out, int out_size, void* d_ws, size_t ws_size,
                              hipStream_t stream) {
  const float* x      = (const float*)d_in[0];
  const int*   ei     = (const int*)d_in[1];
  const float* w_in   = (const float*)d_in[2];
  const float* b_in   = (const float*)d_in[3];
  const float* taps_w = (const float*)d_in[4];
  const float* taps_b = (const float*)d_in[5];
  const float* w_out  = (const float*)d_in[6];
  const float* b_out  = (const float*)d_in[7];

  const int N = in_sizes[0] / 128;
  const int E = in_sizes[1] / 2;
  const int* src = ei;
  const int* dst = ei + E;

  // workspace layout (~55 MB): h, ya fp32 [N,128]; CSR ints. d_out doubles as yb.
  float* h  = (float*)d_ws;
  float* ya = h + (size_t)N * 128;
  float* yb = (float*)d_out;
  int* rowp     = (int*)(ya + (size_t)N * 128);  // N+1
  int* cursor   = rowp + (N + 1);                // N (also used as deg)
  int* esrc     = cursor + N;                    // E
  int* partials = esrc + E;                      // scan partials

  const int scanB = (N + 255) / 256;
  const int edgeB = (E + 255) / 256;
  const int gemmB = (N + 63) / 64;
  const int aggB  = (N + 7) / 8;
  const int eltB  = (N * 32 + 255) / 256;

  // ---- CSR build ----
  hipMemsetAsync(cursor, 0, (size_t)N * 4, stream);
  hist_k<<<edgeB, 256, 0, stream>>>(dst, cursor, E);
  scan1_k<<<scanB, 256, 0, stream>>>(cursor, rowp, partials, N);
  scan2_k<<<1, 256, 0, stream>>>(partials, scanB);
  scan3_k<<<scanB, 256, 0, stream>>>(rowp, partials, cursor, N, E);
  scatter_k<<<edgeB, 256, 0, stream>>>(src, dst, cursor, esrc, E);

  // ---- readin: h = lrelu(x @ w_in + b_in) ----
  gemm128<0><<<gemmB, 256, 0, stream>>>(x, w_in, b_in, h, N);

  // ---- 2 residual graph-filter layers ----
  for (int l = 0; l < 2; l++) {
    const float* tw = taps_w + (size_t)l * 4 * 128 * 128;
    const float* tb = taps_b + (size_t)l * 4 * 128;
    lrelu_k<<<eltB, 256, 0, stream>>>(h, ya, N * 32);
    gemm128<1><<<gemmB, 256, 0, stream>>>(ya, tw, tb, h, N);
    agg_k<<<aggB, 256, 0, stream>>>(ya, yb, rowp, esrc, N);
    gemm128<1><<<gemmB, 256, 0, stream>>>(yb, tw + 128 * 128, tb + 128, h, N);
    agg_k<<<aggB, 256, 0, stream>>>(yb, ya, rowp, esrc, N);
    gemm128<1><<<gemmB, 256, 0, stream>>>(ya, tw + 2 * 128 * 128, tb + 2 * 128, h, N);
    agg_k<<<aggB, 256, 0, stream>>>(ya, yb, rowp, esrc, N);
    gemm128<1><<<gemmB, 256, 0, stream>>>(yb, tw + 3 * 128 * 128, tb + 3 * 128, h, N);
  }

  // ---- readout: d_out = h @ w_out + b_out ----
  gemm128<2><<<gemmB, 256, 0, stream>>>(h, w_out, b_out, (float*)d_out, N);
}

// Round 2
// 494.772 us; speedup vs baseline: 1.7380x; 1.7380x over previous
//
#include <hip/hip_runtime.h>

typedef unsigned int uint;
typedef unsigned short ushort;

using bf16x8 = __attribute__((ext_vector_type(8))) short;
using f32x4  = __attribute__((ext_vector_type(4))) float;

__device__ __forceinline__ float lrelu(float v) { return v > 0.f ? v : 0.01f * v; }
__device__ __forceinline__ float b2f(ushort u) { return __uint_as_float((uint)u << 16); }
__device__ __forceinline__ ushort f2b(float f) {
  uint u = __float_as_uint(f);
  u += 0x7fffu + ((u >> 16) & 1u);   // round-to-nearest-even
  return (ushort)(u >> 16);
}

// ---------------------------------------------------------------------------
// MFMA GEMM: C[N,128] = A[N,128xChunks] @ W[K,128] + bias, bf16 in / fp32 acc.
// A is given as up to 4 chunk pointers, each a [N][128] bf16 buffer (K = 128*chunks).
// Wt is the PRE-TRANSPOSED weight: Wt[n][k], n=0..127, k=0..K-1 (bf16).
// MODE 0: h = lrelu(acc+b) (fp32), yout = bf16(lrelu(h))      (readin)
// MODE 1: h += acc + b                                         (layer taps)
// MODE 2: h = acc + b                                          (readout; h=d_out)
// Tile 64 rows x 128 cols, 256 thr = 4 waves; wave: 2 row-tiles x 4 col-tiles
// of 16x16x32 MFMA.
// ---------------------------------------------------------------------------
template <int MODE, int K>
__global__ __launch_bounds__(256) void gemm_mfma(
    const ushort* __restrict__ A0, const ushort* __restrict__ A1,
    const ushort* __restrict__ A2, const ushort* __restrict__ A3,
    const ushort* __restrict__ Wt, const float* __restrict__ bias,
    float* __restrict__ h, ushort* __restrict__ yout, int N) {
  __shared__ ushort As[64][40];    // [m][k], stride 40 bf16 = 80 B (16B-aligned, 2-way-free banks)
  __shared__ ushort Bs[128][40];   // [n][k]
  const int tid = threadIdx.x;
  const int lane = tid & 63;
  const int wave = tid >> 6;
  const int g = lane >> 4;         // k-quad
  const int mr = lane & 15;
  const int wr = wave >> 1;        // row half
  const int wc = wave & 1;         // col half
  const int row0 = blockIdx.x * 64;

  const ushort* Ap[4] = {A0, A1, A2, A3};

  f32x4 acc[2][4];
#pragma unroll
  for (int i = 0; i < 2; i++)
#pragma unroll
    for (int j = 0; j < 4; j++) acc[i][j] = (f32x4){0.f, 0.f, 0.f, 0.f};

#pragma unroll 4
  for (int kc = 0; kc < K; kc += 32) {
    {  // stage A: 64 rows x 32 k (one uint4 per thread)
      int m = tid >> 2, q = tid & 3;
      int r = row0 + m;
      if (r >= N) r = N - 1;
      int kg = kc + q * 8;
      const ushort* ap = Ap[kg >> 7] + (size_t)r * 128 + (kg & 127);
      *(uint4*)&As[m][q * 8] = *(const uint4*)ap;
    }
#pragma unroll
    for (int t = 0; t < 2; t++) {  // stage B: 128 n x 32 k
      int slot = tid + t * 256;
      int n = slot >> 2, q = slot & 3;
      *(uint4*)&Bs[n][q * 8] = *(const uint4*)(Wt + (size_t)n * K + kc + q * 8);
    }
    __syncthreads();
    bf16x8 af[2], bf[4];
#pragma unroll
    for (int rt = 0; rt < 2; rt++) af[rt] = *(bf16x8*)&As[wr * 32 + rt * 16 + mr][g * 8];
#pragma unroll
    for (int ct = 0; ct < 4; ct++) bf[ct] = *(bf16x8*)&Bs[wc * 64 + ct * 16 + mr][g * 8];
#pragma unroll
    for (int rt = 0; rt < 2; rt++)
#pragma unroll
      for (int ct = 0; ct < 4; ct++)
        acc[rt][ct] = __builtin_amdgcn_mfma_f32_16x16x32_bf16(af[rt], bf[ct], acc[rt][ct], 0, 0, 0);
    __syncthreads();
  }

  // epilogue: C/D layout col=lane&15, row=(lane>>4)*4+reg
#pragma unroll
  for (int rt = 0; rt < 2; rt++) {
#pragma unroll
    for (int i = 0; i < 4; i++) {
      int R = row0 + wr * 32 + rt * 16 + g * 4 + i;
      if (R >= N) continue;
#pragma unroll
      for (int ct = 0; ct < 4; ct++) {
        int c = wc * 64 + ct * 16 + mr;
        float v = acc[rt][ct][i] + bias[c];
        size_t o = (size_t)R * 128 + c;
        if (MODE == 0) {
          float hv = lrelu(v);
          h[o] = hv;
          yout[o] = f2b(lrelu(hv));
        } else if (MODE == 1) {
          h[o] += v;
        } else {
          h[o] = v;
        }
      }
    }
  }
}

// ---------------- bf16 aggregation: out[n] = sum_{e: dst=n} y[src(e)] --------
// 16 lanes per node (uint4 = 8 bf16 each), 16 nodes per 256-thread block.
__global__ __launch_bounds__(256) void agg_bf16(const ushort* __restrict__ yin,
                                                ushort* __restrict__ yout,
                                                const int* __restrict__ rowp,
                                                const int* __restrict__ esrc, int N) {
  int t = threadIdx.x;
  int node = blockIdx.x * 16 + (t >> 4);
  if (node >= N) return;
  int lane = t & 15;
  int beg = rowp[node], end = rowp[node + 1];
  float s[8] = {0.f, 0.f, 0.f, 0.f, 0.f, 0.f, 0.f, 0.f};
  for (int j = beg; j < end; j++) {
    int sn = esrc[j];
    union { uint4 v; ushort u[8]; } w;
    w.v = *(const uint4*)(yin + (size_t)sn * 128 + lane * 8);
#pragma unroll
    for (int e = 0; e < 8; e++) s[e] += b2f(w.u[e]);
  }
  union { uint4 v; ushort u[8]; } o;
#pragma unroll
  for (int e = 0; e < 8; e++) o.u[e] = f2b(s[e]);
  *(uint4*)(yout + (size_t)node * 128 + lane * 8) = o.v;
}

// ---------------- fp32 -> bf16 cast (optionally fused lrelu) -----------------
__global__ __launch_bounds__(256) void cast_f2b(const float* __restrict__ in,
                                                ushort* __restrict__ out, int n8,
                                                int do_lrelu) {
  int i = blockIdx.x * 256 + threadIdx.x;
  if (i >= n8) return;
  float4 a = ((const float4*)in)[i * 2];
  float4 b = ((const float4*)in)[i * 2 + 1];
  float v[8] = {a.x, a.y, a.z, a.w, b.x, b.y, b.z, b.w};
  union { uint4 q; ushort u[8]; } o;
#pragma unroll
  for (int e = 0; e < 8; e++) {
    float f = do_lrelu ? lrelu(v[e]) : v[e];
    o.u[e] = f2b(f);
  }
  ((uint4*)out)[i] = o.q;
}

// ---------------- weight prep: cast + transpose + bias sums ------------------
// regions: [0,16384) Wt_in ; [16384,32768) Wt_out ; [32768,98304) Wt_l0 ;
//          [98304,163840) Wt_l1 ; [163840,164096) bsum
__global__ __launch_bounds__(256) void prep_k(const float* __restrict__ w_in,
                                              const float* __restrict__ w_out,
                                              const float* __restrict__ taps_w,
                                              const float* __restrict__ taps_b,
                                              ushort* __restrict__ Wt_in,
                                              ushort* __restrict__ Wt_out,
                                              ushort* __restrict__ Wt_l0,
                                              ushort* __restrict__ Wt_l1,
                                              float* __restrict__ bsum) {
  int gid = blockIdx.x * 256 + threadIdx.x;
  if (gid < 16384) {
    int n = gid >> 7, k = gid & 127;
    Wt_in[gid] = f2b(w_in[k * 128 + n]);
  } else if (gid < 32768) {
    int i = gid - 16384;
    int n = i >> 7, k = i & 127;
    Wt_out[i] = f2b(w_out[k * 128 + n]);
  } else if (gid < 98304) {
    int i = gid - 32768;
    int n = i >> 9, k = i & 511;
    Wt_l0[i] = f2b(taps_w[(size_t)k * 128 + n]);
  } else if (gid < 163840) {
    int i = gid - 98304;
    int n = i >> 9, k = i & 511;
    Wt_l1[i] = f2b(taps_w[(size_t)(512 + k) * 128 + n]);
  } else if (gid < 164096) {
    int i = gid - 163840;
    int l = i >> 7, n = i & 127;
    float s = 0.f;
    for (int k = 0; k < 4; k++) s += taps_b[l * 512 + k * 128 + n];
    bsum[i] = s;
  }
}

// ---------------- CSR build (unchanged from round 1) -------------------------
__global__ __launch_bounds__(256) void hist_k(const int* __restrict__ dst,
                                              int* __restrict__ deg, int E) {
  int e = blockIdx.x * 256 + threadIdx.x;
  if (e < E) atomicAdd(&deg[dst[e]], 1);
}

__global__ __launch_bounds__(256) void scan1_k(const int* __restrict__ deg,
                                               int* __restrict__ rowp,
                                               int* __restrict__ partials, int N) {
  __shared__ int sm[256];
  int i = blockIdx.x * 256 + threadIdx.x;
  int v = (i < N) ? deg[i] : 0;
  int x = v;
  sm[threadIdx.x] = v;
  __syncthreads();
  for (int off = 1; off < 256; off <<= 1) {
    int t = (threadIdx.x >= off) ? sm[threadIdx.x - off] : 0;
    __syncthreads();
    x += t;
    sm[threadIdx.x] = x;
    __syncthreads();
  }
  if (i < N) rowp[i] = x - v;
  if (threadIdx.x == 255) partials[blockIdx.x] = x;
}

__global__ __launch_bounds__(256) void scan2_k(int* __restrict__ partials, int P) {
  __shared__ int sm[256];
  int i = threadIdx.x;
  int v = (i < P) ? partials[i] : 0;
  int x = v;
  sm[i] = v;
  __syncthreads();
  for (int off = 1; off < 256; off <<= 1) {
    int t = (i >= off) ? sm[i - off] : 0;
    __syncthreads();
    x += t;
    sm[i] = x;
    __syncthreads();
  }
  if (i < P) partials[i] = x - v;
}

__global__ __launch_bounds__(256) void scan3_k(int* __restrict__ rowp,
                                               const int* __restrict__ partials,
                                               int* __restrict__ cursor, int N, int E) {
  int i = blockIdx.x * 256 + threadIdx.x;
  if (i < N) {
    int v = rowp[i] + partials[blockIdx.x];
    rowp[i] = v;
    cursor[i] = v;
  }
  if (i == 0) rowp[N] = E;
}

__global__ __launch_bounds__(256) void scatter_k(const int* __restrict__ src,
                                                 const int* __restrict__ dst,
                                                 int* __restrict__ cursor,
                                                 int* __restrict__ esrc, int E) {
  int e = blockIdx.x * 256 + threadIdx.x;
  if (e < E) {
    int pos = atomicAdd(&cursor[dst[e]], 1);
    esrc[pos] = src[e];
  }
}

// ---------------------------------------------------------------------------
extern "C" void kernel_launch(void* const* d_in, const int* in_sizes, int n_in,
                              void* d_out, int out_size, void* d_ws, size_t ws_size,
                              hipStream_t stream) {
  const float* x      = (const float*)d_in[0];
  const int*   ei     = (const int*)d_in[1];
  const float* w_in   = (const float*)d_in[2];
  const float* b_in   = (const float*)d_in[3];
  const float* taps_w = (const float*)d_in[4];
  const float* taps_b = (const float*)d_in[5];
  const float* w_out  = (const float*)d_in[6];
  const float* b_out  = (const float*)d_in[7];

  const int N = in_sizes[0] / 128;
  const int E = in_sizes[1] / 2;
  const int* src = ei;
  const int* dst = ei + E;

  // h (fp32) lives in d_out until the readout GEMM overwrites it.
  float* h = (float*)d_out;

  // workspace (~55 MB): 4 bf16 y-buffers, bf16 weights, CSR ints
  const size_t ybytes = (size_t)N * 128;  // elements per y buffer
  ushort* y0 = (ushort*)d_ws;
  ushort* y1 = y0 + ybytes;
  ushort* y2 = y1 + ybytes;
  ushort* y3 = y2 + ybytes;
  ushort* Wt_in  = y3 + ybytes;            // 128*128
  ushort* Wt_out = Wt_in + 128 * 128;      // 128*128
  ushort* Wt_l0  = Wt_out + 128 * 128;     // 128*512
  ushort* Wt_l1  = Wt_l0 + 128 * 512;      // 128*512
  float*  bsum   = (float*)(Wt_l1 + 128 * 512);  // 256
  int* rowp     = (int*)(bsum + 256);      // N+1
  int* cursor   = rowp + (N + 1);          // N
  int* esrc     = cursor + N;              // E
  int* partials = esrc + E;                // scan partials

  const int scanB = (N + 255) / 256;
  const int edgeB = (E + 255) / 256;
  const int gemmB = (N + 63) / 64;
  const int aggB  = (N + 15) / 16;
  const int castB = (N * 16 + 255) / 256;

  // ---- CSR build ----
  hipMemsetAsync(cursor, 0, (size_t)N * 4, stream);
  hist_k<<<edgeB, 256, 0, stream>>>(dst, cursor, E);
  scan1_k<<<scanB, 256, 0, stream>>>(cursor, rowp, partials, N);
  scan2_k<<<1, 256, 0, stream>>>(partials, scanB);
  scan3_k<<<scanB, 256, 0, stream>>>(rowp, partials, cursor, N, E);
  scatter_k<<<edgeB, 256, 0, stream>>>(src, dst, cursor, esrc, E);

  // ---- weight prep + x cast (x -> y1; readin reads y1, writes y0) ----
  prep_k<<<641, 256, 0, stream>>>(w_in, w_out, taps_w, taps_b,
                                  Wt_in, Wt_out, Wt_l0, Wt_l1, bsum);
  cast_f2b<<<castB, 256, 0, stream>>>(x, y1, N * 16, 0);

  // ---- readin: h = lrelu(x@Win+b); y0 = bf16(lrelu(h)) ----
  gemm_mfma<0, 128><<<gemmB, 256, 0, stream>>>(y1, y1, y1, y1, Wt_in, b_in, h, y0, N);

  // ---- 2 residual graph-filter layers ----
  for (int l = 0; l < 2; l++) {
    const ushort* Wt_l = (l == 0) ? Wt_l0 : Wt_l1;
    agg_bf16<<<aggB, 256, 0, stream>>>(y0, y1, rowp, esrc, N);
    agg_bf16<<<aggB, 256, 0, stream>>>(y1, y2, rowp, esrc, N);
    agg_bf16<<<aggB, 256, 0, stream>>>(y2, y3, rowp, esrc, N);
    gemm_mfma<1, 512><<<gemmB, 256, 0, stream>>>(y0, y1, y2, y3, Wt_l, bsum + l * 128,
                                                 h, nullptr, N);
    // y0 <- bf16(lrelu(h)) for next layer; bf16(h) for readout after last layer
    cast_f2b<<<castB, 256, 0, stream>>>(h, y0, N * 16, (l == 0) ? 1 : 0);
  }

  // ---- readout: d_out = h @ Wout + bout (reads y0 = bf16(h)) ----
  gemm_mfma<2, 128><<<gemmB, 256, 0, stream>>>(y0, y0, y0, y0, Wt_out, b_out,
                                               (float*)d_out, nullptr, N);
}

// Round 3
// 409.993 us; speedup vs baseline: 2.0974x; 1.2068x over previous
//
#include <hip/hip_runtime.h>

typedef unsigned int uint;
typedef unsigned short ushort;

using bf16x8 = __attribute__((ext_vector_type(8))) short;
using f32x4  = __attribute__((ext_vector_type(4))) float;

__device__ __forceinline__ float lrelu(float v) { return v > 0.f ? v : 0.01f * v; }
__device__ __forceinline__ float b2f(ushort u) { return __uint_as_float((uint)u << 16); }
__device__ __forceinline__ ushort f2b(float f) {
  uint u = __float_as_uint(f);
  u += 0x7fffu + ((u >> 16) & 1u);   // round-to-nearest-even
  return (ushort)(u >> 16);
}

#define CSR_B 256          // blocks in coarse passes
#define BKT_SHIFT 10       // 1024 dst nodes per bucket
#define MAX_NB 64          // max buckets (N <= 65536)

// ---------------------------------------------------------------------------
// MFMA GEMM: C[N,128] = A[N,K] @ W[K,128] + bias, bf16 in / fp32 acc.
// A given as up to 4 chunk pointers, each [N][128] bf16 (K = 128*chunks).
// Wt pre-transposed: Wt[n][k] bf16.
// MODE 0: h = lrelu(acc+b); yout = bf16(lrelu(h))           (readin)
// MODE 1: h += acc+b; if yout: yout = bf16(act? lrelu(h):h) (layer taps, fused cast)
// MODE 2: h = acc+b                                          (readout)
// ---------------------------------------------------------------------------
template <int MODE, int K>
__global__ __launch_bounds__(256) void gemm_mfma(
    const ushort* __restrict__ A0, const ushort* __restrict__ A1,
    const ushort* __restrict__ A2, const ushort* __restrict__ A3,
    const ushort* __restrict__ Wt, const float* __restrict__ bias,
    float* __restrict__ h, ushort* __restrict__ yout, int do_act, int N) {
  __shared__ ushort As[64][40];    // [m][k], stride 40 (16B-aligned, 2-way-free banks)
  __shared__ ushort Bs[128][40];   // [n][k]
  const int tid = threadIdx.x;
  const int lane = tid & 63;
  const int wave = tid >> 6;
  const int g = lane >> 4;         // k-quad
  const int mr = lane & 15;
  const int wr = wave >> 1;        // row half
  const int wc = wave & 1;         // col half
  const int row0 = blockIdx.x * 64;

  const ushort* Ap[4] = {A0, A1, A2, A3};

  f32x4 acc[2][4];
#pragma unroll
  for (int i = 0; i < 2; i++)
#pragma unroll
    for (int j = 0; j < 4; j++) acc[i][j] = (f32x4){0.f, 0.f, 0.f, 0.f};

#pragma unroll 4
  for (int kc = 0; kc < K; kc += 32) {
    {  // stage A: 64 rows x 32 k (one uint4 per thread)
      int m = tid >> 2, q = tid & 3;
      int r = row0 + m;
      if (r >= N) r = N - 1;
      int kg = kc + q * 8;
      const ushort* ap = Ap[kg >> 7] + (size_t)r * 128 + (kg & 127);
      *(uint4*)&As[m][q * 8] = *(const uint4*)ap;
    }
#pragma unroll
    for (int t = 0; t < 2; t++) {  // stage B: 128 n x 32 k
      int slot = tid + t * 256;
      int n = slot >> 2, q = slot & 3;
      *(uint4*)&Bs[n][q * 8] = *(const uint4*)(Wt + (size_t)n * K + kc + q * 8);
    }
    __syncthreads();
    bf16x8 af[2], bf[4];
#pragma unroll
    for (int rt = 0; rt < 2; rt++) af[rt] = *(bf16x8*)&As[wr * 32 + rt * 16 + mr][g * 8];
#pragma unroll
    for (int ct = 0; ct < 4; ct++) bf[ct] = *(bf16x8*)&Bs[wc * 64 + ct * 16 + mr][g * 8];
#pragma unroll
    for (int rt = 0; rt < 2; rt++)
#pragma unroll
      for (int ct = 0; ct < 4; ct++)
        acc[rt][ct] = __builtin_amdgcn_mfma_f32_16x16x32_bf16(af[rt], bf[ct], acc[rt][ct], 0, 0, 0);
    __syncthreads();
  }

  // epilogue: C/D layout col=lane&15, row=(lane>>4)*4+reg
#pragma unroll
  for (int rt = 0; rt < 2; rt++) {
#pragma unroll
    for (int i = 0; i < 4; i++) {
      int R = row0 + wr * 32 + rt * 16 + g * 4 + i;
      if (R >= N) continue;
#pragma unroll
      for (int ct = 0; ct < 4; ct++) {
        int c = wc * 64 + ct * 16 + mr;
        float v = acc[rt][ct][i] + bias[c];
        size_t o = (size_t)R * 128 + c;
        if (MODE == 0) {
          float hv = lrelu(v);
          h[o] = hv;
          yout[o] = f2b(lrelu(hv));
        } else if (MODE == 1) {
          float hv = h[o] + v;
          h[o] = hv;
          if (yout) yout[o] = f2b(do_act ? lrelu(hv) : hv);
        } else {
          h[o] = v;
        }
      }
    }
  }
}

// ---------------- bf16 aggregation: out[n] = sum_{e: dst=n} y[src(e)] --------
// 16 lanes per node (uint4 = 8 bf16 each), 16 nodes per 256-thread block.
// 4-way unrolled gather for memory-level parallelism.
__global__ __launch_bounds__(256) void agg_bf16(const ushort* __restrict__ yin,
                                                ushort* __restrict__ yout,
                                                const int* __restrict__ rowp,
                                                const ushort* __restrict__ esrc, int N) {
  int t = threadIdx.x;
  int node = blockIdx.x * 16 + (t >> 4);
  if (node >= N) return;
  int lane = t & 15;
  int beg = rowp[node], end = rowp[node + 1];
  float s[8] = {0.f, 0.f, 0.f, 0.f, 0.f, 0.f, 0.f, 0.f};
  int j = beg;
  for (; j + 4 <= end; j += 4) {
    int s0 = esrc[j], s1 = esrc[j + 1], s2 = esrc[j + 2], s3 = esrc[j + 3];
    union { uint4 v; ushort u[8]; } w0, w1, w2, w3;
    w0.v = *(const uint4*)(yin + (size_t)s0 * 128 + lane * 8);
    w1.v = *(const uint4*)(yin + (size_t)s1 * 128 + lane * 8);
    w2.v = *(const uint4*)(yin + (size_t)s2 * 128 + lane * 8);
    w3.v = *(const uint4*)(yin + (size_t)s3 * 128 + lane * 8);
#pragma unroll
    for (int e = 0; e < 8; e++)
      s[e] += (b2f(w0.u[e]) + b2f(w1.u[e])) + (b2f(w2.u[e]) + b2f(w3.u[e]));
  }
  for (; j < end; j++) {
    int sn = esrc[j];
    union { uint4 v; ushort u[8]; } w;
    w.v = *(const uint4*)(yin + (size_t)sn * 128 + lane * 8);
#pragma unroll
    for (int e = 0; e < 8; e++) s[e] += b2f(w.u[e]);
  }
  union { uint4 v; ushort u[8]; } o;
#pragma unroll
  for (int e = 0; e < 8; e++) o.u[e] = f2b(s[e]);
  *(uint4*)(yout + (size_t)node * 128 + lane * 8) = o.v;
}

// ---------------- fp32 -> bf16 cast ----------------
__global__ __launch_bounds__(256) void cast_f2b(const float* __restrict__ in,
                                                ushort* __restrict__ out, int n8) {
  int i = blockIdx.x * 256 + threadIdx.x;
  if (i >= n8) return;
  float4 a = ((const float4*)in)[i * 2];
  float4 b = ((const float4*)in)[i * 2 + 1];
  float v[8] = {a.x, a.y, a.z, a.w, b.x, b.y, b.z, b.w};
  union { uint4 q; ushort u[8]; } o;
#pragma unroll
  for (int e = 0; e < 8; e++) o.u[e] = f2b(v[e]);
  ((uint4*)out)[i] = o.q;
}

// ---------------- weight prep: cast + transpose + bias sums ------------------
__global__ __launch_bounds__(256) void prep_k(const float* __restrict__ w_in,
                                              const float* __restrict__ w_out,
                                              const float* __restrict__ taps_w,
                                              const float* __restrict__ taps_b,
                                              ushort* __restrict__ Wt_in,
                                              ushort* __restrict__ Wt_out,
                                              ushort* __restrict__ Wt_l0,
                                              ushort* __restrict__ Wt_l1,
                                              float* __restrict__ bsum) {
  int gid = blockIdx.x * 256 + threadIdx.x;
  if (gid < 16384) {
    int n = gid >> 7, k = gid & 127;
    Wt_in[gid] = f2b(w_in[k * 128 + n]);
  } else if (gid < 32768) {
    int i = gid - 16384;
    int n = i >> 7, k = i & 127;
    Wt_out[i] = f2b(w_out[k * 128 + n]);
  } else if (gid < 98304) {
    int i = gid - 32768;
    int n = i >> 9, k = i & 511;
    Wt_l0[i] = f2b(taps_w[(size_t)k * 128 + n]);
  } else if (gid < 163840) {
    int i = gid - 98304;
    int n = i >> 9, k = i & 511;
    Wt_l1[i] = f2b(taps_w[(size_t)(512 + k) * 128 + n]);
  } else if (gid < 164096) {
    int i = gid - 163840;
    int l = i >> 7, n = i & 127;
    float s = 0.f;
    for (int k = 0; k < 4; k++) s += taps_b[l * 512 + k * 128 + n];
    bsum[i] = s;
  }
}

// ---------------- CSR build: 2-level binned counting sort --------------------
// Pass 1: per-(block,bucket) histogram. H[bucket][block], bucket = dst>>10.
__global__ __launch_bounds__(256) void chist_k(const int* __restrict__ dst,
                                               int* __restrict__ H, int E, int NB) {
  __shared__ int hh[MAX_NB];
  if (threadIdx.x < NB) hh[threadIdx.x] = 0;
  __syncthreads();
  int chunk = (E + gridDim.x - 1) / gridDim.x;
  int beg = blockIdx.x * chunk, end = min(E, beg + chunk);
  for (int e = beg + threadIdx.x; e < end; e += 256)
    atomicAdd(&hh[dst[e] >> BKT_SHIFT], 1);
  __syncthreads();
  if (threadIdx.x < NB) H[threadIdx.x * gridDim.x + blockIdx.x] = hh[threadIdx.x];
}

// Pass 2: exclusive scan of H (M = NB*CSR_B entries), single block.
__global__ __launch_bounds__(256) void cscan_k(int* __restrict__ H, int M) {
  __shared__ int sm[256];
  int per = (M + 255) / 256;
  int b0 = threadIdx.x * per;
  int hi = min(M, b0 + per);
  int sum = 0;
  for (int i = b0; i < hi; i++) sum += H[i];
  sm[threadIdx.x] = sum;
  __syncthreads();
  int x = sum;
  for (int off = 1; off < 256; off <<= 1) {
    int tt = (threadIdx.x >= off) ? sm[threadIdx.x - off] : 0;
    __syncthreads();
    x += tt;
    sm[threadIdx.x] = x;
    __syncthreads();
  }
  int run = x - sum;  // exclusive
  for (int i = b0; i < hi; i++) {
    int v = H[i];
    H[i] = run;
    run += v;
  }
}

// Pass 3: coarse scatter into bucket regions, packed (dst<<16)|src.
__global__ __launch_bounds__(256) void cscatter_k(const int* __restrict__ src,
                                                  const int* __restrict__ dst,
                                                  const int* __restrict__ H,
                                                  uint* __restrict__ packed,
                                                  int E, int NB) {
  __shared__ int cur[MAX_NB];
  int chunk = (E + gridDim.x - 1) / gridDim.x;
  int beg = blockIdx.x * chunk, end = min(E, beg + chunk);
  if (threadIdx.x < NB) cur[threadIdx.x] = H[threadIdx.x * gridDim.x + blockIdx.x];
  __syncthreads();
  for (int e = beg + threadIdx.x; e < end; e += 256) {
    int d = dst[e];
    int pos = atomicAdd(&cur[d >> BKT_SHIFT], 1);
    packed[pos] = ((uint)d << 16) | (uint)src[e];
  }
}

// Pass 4: per-bucket exact sort by dst (LDS hist+scan+cursors) -> esrc + rowp.
__global__ __launch_bounds__(256) void fsort_k(const uint* __restrict__ packed,
                                               const int* __restrict__ H,
                                               ushort* __restrict__ esrc,
                                               int* __restrict__ rowp,
                                               int N, int E, int NB) {
  __shared__ int hist[1 << BKT_SHIFT];
  __shared__ int cur[1 << BKT_SHIFT];
  __shared__ int sm[256];
  const int bkt = blockIdx.x;
  const int base = bkt << BKT_SHIFT;
  const int nb_nodes = min(1 << BKT_SHIFT, N - base);
  const int start = H[bkt * CSR_B];
  const int end = (bkt == NB - 1) ? E : H[(bkt + 1) * CSR_B];

  for (int i = threadIdx.x; i < (1 << BKT_SHIFT); i += 256) hist[i] = 0;
  __syncthreads();
  for (int e = start + threadIdx.x; e < end; e += 256)
    atomicAdd(&hist[(packed[e] >> 16) - base], 1);
  __syncthreads();

  // exclusive scan of hist into cur (+start); also write rowp
  int t4 = threadIdx.x * 4;
  int l0 = hist[t4], l1 = hist[t4 + 1], l2 = hist[t4 + 2], l3 = hist[t4 + 3];
  int ssum = l0 + l1 + l2 + l3;
  sm[threadIdx.x] = ssum;
  __syncthreads();
  int x = ssum;
  for (int off = 1; off < 256; off <<= 1) {
    int tt = (threadIdx.x >= off) ? sm[threadIdx.x - off] : 0;
    __syncthreads();
    x += tt;
    sm[threadIdx.x] = x;
    __syncthreads();
  }
  int c0 = start + x - ssum;
  int c1 = c0 + l0, c2 = c1 + l1, c3 = c2 + l2;
  cur[t4] = c0; cur[t4 + 1] = c1; cur[t4 + 2] = c2; cur[t4 + 3] = c3;
  if (t4 + 0 < nb_nodes) rowp[base + t4 + 0] = c0;
  if (t4 + 1 < nb_nodes) rowp[base + t4 + 1] = c1;
  if (t4 + 2 < nb_nodes) rowp[base + t4 + 2] = c2;
  if (t4 + 3 < nb_nodes) rowp[base + t4 + 3] = c3;
  __syncthreads();

  for (int e = start + threadIdx.x; e < end; e += 256) {
    uint p = packed[e];
    int pos = atomicAdd(&cur[(p >> 16) - base], 1);
    esrc[pos] = (ushort)(p & 0xffffu);
  }
  if (bkt == 0 && threadIdx.x == 0) rowp[N] = E;
}

// ---------------------------------------------------------------------------
extern "C" void kernel_launch(void* const* d_in, const int* in_sizes, int n_in,
                              void* d_out, int out_size, void* d_ws, size_t ws_size,
                              hipStream_t stream) {
  const float* x      = (const float*)d_in[0];
  const int*   ei     = (const int*)d_in[1];
  const float* w_in   = (const float*)d_in[2];
  const float* b_in   = (const float*)d_in[3];
  const float* taps_w = (const float*)d_in[4];
  const float* taps_b = (const float*)d_in[5];
  const float* w_out  = (const float*)d_in[6];
  const float* b_out  = (const float*)d_in[7];

  const int N = in_sizes[0] / 128;
  const int E = in_sizes[1] / 2;
  const int* src = ei;
  const int* dst = ei + E;
  const int NB = (N + (1 << BKT_SHIFT) - 1) >> BKT_SHIFT;  // buckets (<= MAX_NB)

  // h (fp32) lives in d_out until the readout GEMM overwrites it.
  float* h = (float*)d_out;

  // workspace (~57 MB)
  const size_t yelem = (size_t)N * 128;
  ushort* y0 = (ushort*)d_ws;
  ushort* y1 = y0 + yelem;
  ushort* y2 = y1 + yelem;
  ushort* y3 = y2 + yelem;
  ushort* Wt_in  = y3 + yelem;             // 128*128
  ushort* Wt_out = Wt_in + 128 * 128;      // 128*128
  ushort* Wt_l0  = Wt_out + 128 * 128;     // 128*512
  ushort* Wt_l1  = Wt_l0 + 128 * 512;      // 128*512
  float*  bsum   = (float*)(Wt_l1 + 128 * 512);   // 256
  int*    rowp   = (int*)(bsum + 256);     // N+1
  int*    H      = rowp + (N + 1);         // NB*CSR_B
  uint*   packed = (uint*)(H + MAX_NB * CSR_B);   // E
  ushort* esrc   = (ushort*)(packed + E);  // E

  const int gemmB = (N + 63) / 64;
  const int aggB  = (N + 15) / 16;
  const int castB = (N * 16 + 255) / 256;

  // ---- CSR build (binned counting sort) ----
  chist_k<<<CSR_B, 256, 0, stream>>>(dst, H, E, NB);
  cscan_k<<<1, 256, 0, stream>>>(H, NB * CSR_B);
  cscatter_k<<<CSR_B, 256, 0, stream>>>(src, dst, H, packed, E, NB);
  fsort_k<<<NB, 256, 0, stream>>>(packed, H, esrc, rowp, N, E, NB);

  // ---- weight prep + x cast ----
  prep_k<<<641, 256, 0, stream>>>(w_in, w_out, taps_w, taps_b,
                                  Wt_in, Wt_out, Wt_l0, Wt_l1, bsum);
  cast_f2b<<<castB, 256, 0, stream>>>(x, y1, N * 16);

  // ---- readin: h = lrelu(x@Win+b); y0 = bf16(lrelu(h)) ----
  gemm_mfma<0, 128><<<gemmB, 256, 0, stream>>>(y1, y1, y1, y1, Wt_in, b_in, h, y0, 0, N);

  // ---- 2 residual graph-filter layers (cast fused into GEMM epilogue) ----
  for (int l = 0; l < 2; l++) {
    const ushort* Wt_l = (l == 0) ? Wt_l0 : Wt_l1;
    agg_bf16<<<aggB, 256, 0, stream>>>(y0, y1, rowp, esrc, N);
    agg_bf16<<<aggB, 256, 0, stream>>>(y1, y2, rowp, esrc, N);
    agg_bf16<<<aggB, 256, 0, stream>>>(y2, y3, rowp, esrc, N);
    // fused: y0 <- bf16(lrelu(h)) for next layer (l=0) / bf16(h) for readout (l=1)
    gemm_mfma<1, 512><<<gemmB, 256, 0, stream>>>(y0, y1, y2, y3, Wt_l, bsum + l * 128,
                                                 h, y0, (l == 0) ? 1 : 0, N);
  }

  // ---- readout: d_out = h @ Wout + bout (reads y0 = bf16(h)) ----
  gemm_mfma<2, 128><<<gemmB, 256, 0, stream>>>(y0, y0, y0, y0, Wt_out, b_out,
                                               (float*)d_out, nullptr, 0, N);
}